// Round 13
// baseline (124.675 us; speedup 1.0000x reference)
//
#include <hip/hip_runtime.h>

#define GAT_ALPHA 0.2f
#define INV_N (1.0f / 2048.0f)
#define ZI(j) ((j) + ((j) >> 5))   // LDS bank swizzle for z_s

typedef float f32x4 __attribute__((ext_vector_type(4)));
typedef int   i32x4 __attribute__((ext_vector_type(4)));
typedef __bf16 bf16x8 __attribute__((ext_vector_type(8)));
typedef unsigned short us8 __attribute__((ext_vector_type(8)));
typedef unsigned short us4 __attribute__((ext_vector_type(4)));

__device__ __forceinline__ unsigned short f2bf(float x) {
  union { float f; unsigned u; } v; v.f = x;
  unsigned r = v.u + 0x7FFFu + ((v.u >> 16) & 1u);   // RNE
  return (unsigned short)(r >> 16);
}
__device__ __forceinline__ float lrelu(float x) {
  return fmaxf(x, 0.f) + GAT_ALPHA * fminf(x, 0.f);
}
__device__ __forceinline__ void lgkm_barrier() {
  asm volatile("s_waitcnt lgkmcnt(0)" ::: "memory");
  __builtin_amdgcn_s_barrier();
  __builtin_amdgcn_sched_barrier(0);
}

// ---------------- k0: Wh = h @ W (f32), s1/s2, WhT in bf16 [b][f][j] ----------------
__global__ __launch_bounds__(256)
void k0_wh(const float* __restrict__ h, const float* __restrict__ W,
           const float* __restrict__ a, unsigned short* __restrict__ WhT,
           float* __restrict__ s1g, float* __restrict__ s2g)
{
  __shared__ float h_s[64][132];
  __shared__ float W_s[128][64];
  __shared__ float wt_s[64][66];
  __shared__ float a_s[128];
  const int t = threadIdx.x;
  const int b = blockIdx.y;
  const int r0 = blockIdx.x * 64;

#pragma unroll
  for (int v = 0; v < 8; ++v) {
    int c = v * 256 + t;
    int k = c >> 4, fo = (c & 15) << 2;
    *(float4*)&W_s[k][fo] = *(const float4*)&W[k * 64 + fo];
  }
#pragma unroll
  for (int v = 0; v < 8; ++v) {
    int c = v * 256 + t;
    int r = c >> 5, ko = (c & 31) << 2;
    *(float4*)&h_s[r][ko] = *(const float4*)&h[((size_t)(b * 2048 + r0 + r)) * 128 + ko];
  }
  if (t < 128) a_s[t] = a[t];
  __syncthreads();

  const int tg = t >> 4;          // 0..15
  const int tf = (t & 15) << 2;   // f base
  float acc[4][4] = {};
#pragma unroll
  for (int k4 = 0; k4 < 32; ++k4) {
    float4 hv[4];
#pragma unroll
    for (int i = 0; i < 4; ++i)
      hv[i] = *(const float4*)&h_s[i * 16 + tg][k4 * 4];
#pragma unroll
    for (int kk = 0; kk < 4; ++kk) {
      float4 wv = *(const float4*)&W_s[k4 * 4 + kk][tf];
#pragma unroll
      for (int i = 0; i < 4; ++i) {
        float hx = ((const float*)&hv[i])[kk];
        acc[i][0] = fmaf(hx, wv.x, acc[i][0]);
        acc[i][1] = fmaf(hx, wv.y, acc[i][1]);
        acc[i][2] = fmaf(hx, wv.z, acc[i][2]);
        acc[i][3] = fmaf(hx, wv.w, acc[i][3]);
      }
    }
  }
#pragma unroll
  for (int i = 0; i < 4; ++i)
#pragma unroll
    for (int j = 0; j < 4; ++j)
      wt_s[tf + j][i * 16 + tg] = acc[i][j];
  __syncthreads();

  if (t < 64) {   // s1/s2 for row r = t (f32 exact)
    float v1 = 0.f, v2 = 0.f;
#pragma unroll 8
    for (int f = 0; f < 64; ++f) {
      float w = wt_s[f][t];
      v1 = fmaf(w, a_s[f], v1);
      v2 = fmaf(w, a_s[64 + f], v2);
    }
    s1g[b * 2048 + r0 + t] = v1;
    s2g[b * 2048 + r0 + t] = v2;
  }
  {  // WhT bf16 write, [b][f][j]
    int f = t >> 2, rb = (t & 3) << 4;
    unsigned short pk[16];
#pragma unroll
    for (int i = 0; i < 16; ++i) pk[i] = f2bf(wt_s[f][rb + i]);
    size_t base = ((size_t)(b * 64 + f)) * 2048 + r0 + rb;
    *(uint4*)&WhT[base]     = *(uint4*)&pk[0];
    *(uint4*)&WhT[base + 8] = *(uint4*)&pk[8];
  }
}

// ---------------- k12: fused stats + att write (nt) + PV MFMA + ELU ----------------
// R11 structure, ONE delta: wreg (Wh tile) prefetched ONE ITERATION AHEAD and
// written to wh_s at the TOP of the next iter. The vmcnt wait before that
// ds_write only covers loads older than the previous iter's stores, so in-flight
// nt att stores are never drained. MFMA operands remain strictly in LDS (lgkm).
__global__ __launch_bounds__(256, 4)
void k12_main(const int* __restrict__ adj, const unsigned short* __restrict__ WhT,
              const float* __restrict__ s1g, const float* __restrict__ s2g,
              float* __restrict__ hout, float* __restrict__ att)
{
  __shared__ float z_s[2112];                 // swizzled, 8.25 KB
  __shared__ unsigned short bm16[16][128];    // 4 KB: bit (j&15) of word j>>4
  __shared__ float s1_s[16], il_s[16];
  __shared__ unsigned short att_s[16][136];   // bf16 att tile (stride 272 B)
  __shared__ unsigned short wh_s[64][136];    // bf16 Wh tile [f][k]

  const int t = threadIdx.x;
  const int b = blockIdx.y;
  const int r0 = blockIdx.x * 16;
  const size_t rowb = (size_t)(b * 2048 + r0);
  const int r = t >> 4, q = t & 15;           // pass-1: 16 threads per row
  const int* __restrict__ arow = adj + (rowb + r) * 2048;

  // issue first adj batch BEFORE staging barrier (loads fly across lgkm_barrier)
  i32x4 av0[4], av1[4];
#pragma unroll
  for (int k = 0; k < 4; ++k) av0[k] = *(const i32x4*)&arow[q * 16 + 4 * k];

  // stage z_s (s2 row, swizzled) + s1_s
  {
    const float4 za = *(const float4*)&s2g[b * 2048 + t * 8];
    const float4 zb = *(const float4*)&s2g[b * 2048 + t * 8 + 4];
    *(float4*)&z_s[ZI(t * 8)]     = za;
    *(float4*)&z_s[ZI(t * 8 + 4)] = zb;
  }
  if (t < 16) s1_s[t] = s1g[rowb + t];
  const float s1v = s1g[rowb + r];
  lgkm_barrier();   // z_s visible; adj loads still in flight

  // ---- pass 1: masks + denominator (8 int4 in flight via double buffer) ----
  float sum = 0.f;
#pragma unroll
  for (int c = 0; c < 8; ++c) {
    if (c < 7) {
#pragma unroll
      for (int k = 0; k < 4; ++k)
        av1[k] = *(const i32x4*)&arow[(c + 1) * 256 + q * 16 + 4 * k];
    }
    unsigned bits = 0;
#pragma unroll
    for (int k = 0; k < 4; ++k) {
      const float4 z = *(const float4*)&z_s[ZI(c * 256 + q * 16 + 4 * k)];
      const bool p0 = av0[k].x > 0, p1 = av0[k].y > 0;
      const bool p2 = av0[k].z > 0, p3 = av0[k].w > 0;
      bits |= (unsigned(p0) | (unsigned(p1) << 1) |
               (unsigned(p2) << 2) | (unsigned(p3) << 3)) << (4 * k);
      sum += p0 ? __expf(lrelu(s1v + z.x)) : 0.f;
      sum += p1 ? __expf(lrelu(s1v + z.y)) : 0.f;
      sum += p2 ? __expf(lrelu(s1v + z.z)) : 0.f;
      sum += p3 ? __expf(lrelu(s1v + z.w)) : 0.f;
    }
    bm16[r][c * 16 + q] = (unsigned short)bits;
#pragma unroll
    for (int k = 0; k < 4; ++k) av0[k] = av1[k];
  }
#pragma unroll
  for (int o = 1; o < 16; o <<= 1) sum += __shfl_xor(sum, o);
  if (q == 0) il_s[r] = (sum > 0.f) ? 1.f / sum : -1.f;  // -1: no neighbors -> 1/N
  lgkm_barrier();   // bm16 + il_s visible

  // ---- pass 2: att write (nt) + PV; wreg prefetched 1 iter ahead ----
  const int w  = t >> 6, l = t & 63;
  const int ln = l & 15, lg = l >> 4;
  const int ff = t >> 4, ko = (t & 15) << 3;   // wh staging coords
  const int jj = (t & 31) << 2;
  const int rbase = t >> 5;
  f32x4 acc = {0.f, 0.f, 0.f, 0.f};

  // prologue: prefetch iter-0's Wh tile (oldest vmem ops, before any store)
  uint4 wregN[4];
#pragma unroll
  for (int v = 0; v < 4; ++v)
    wregN[v] = *(const uint4*)&WhT[((size_t)(b * 64 + v * 16 + ff)) * 2048 + ko];

  for (int j0 = 0; j0 < 2048; j0 += 128) {
    // consume prefetched tile: vmcnt wait here only covers loads issued BEFORE
    // the previous iter's stores -> no store drain
#pragma unroll
    for (int v = 0; v < 4; ++v)
      *(uint4*)&wh_s[v * 16 + ff][ko] = wregN[v];
    __builtin_amdgcn_sched_barrier(0);

    // prefetch NEXT iter's tile BEFORE this iter's stores (stays older than them)
    const int jpf = (j0 + 128) & 2047;   // wraps harmlessly on last iter
#pragma unroll
    for (int v = 0; v < 4; ++v)
      wregN[v] = *(const uint4*)&WhT[((size_t)(b * 64 + v * 16 + ff)) * 2048 + jpf + ko];
    __builtin_amdgcn_sched_barrier(0);

    // attention: 16 rows x 128 j; z read once, used for both row-halves
    const int j = j0 + jj;
    const float4 zv = *(const float4*)&z_s[ZI(j)];
#pragma unroll
    for (int it = 0; it < 2; ++it) {
      const int rr = rbase + (it << 3);
      const float s1r = s1_s[rr], il = il_s[rr];
      const bool uni = (il < 0.f);
      const unsigned mb = (unsigned)bm16[rr][j >> 4] >> (j & 15);
      f32x4 o;
#define PW(dst, zz, k)                                              \
      { float e = __expf(lrelu(s1r + (zz))) * il;                   \
        dst = uni ? INV_N : (((mb >> (k)) & 1u) ? e : 0.f); }
      PW(o[0], zv.x, 0) PW(o[1], zv.y, 1) PW(o[2], zv.z, 2) PW(o[3], zv.w, 3)
#undef PW
      __builtin_nontemporal_store(o, (f32x4*)&att[(rowb + rr) * 2048 + j]);
      us4 pk;
      pk.x = f2bf(o[0]); pk.y = f2bf(o[1]); pk.z = f2bf(o[2]); pk.w = f2bf(o[3]);
      *(us4*)&att_s[rr][jj] = pk;
    }

    lgkm_barrier();   // publish att_s + wh_s; nt stores + prefetch NOT drained
    // PV: wave w owns f-tile w; A from att_s, B from wh_s (same k-permutation)
#pragma unroll
    for (int ks = 0; ks < 4; ++ks) {
      union { us8 u; bf16x8 v; } ac, bc;
      ac.u = *(const us8*)&att_s[ln][ks * 32 + lg * 8];
      bc.u = *(const us8*)&wh_s[w * 16 + ln][ks * 32 + lg * 8];
      acc = __builtin_amdgcn_mfma_f32_16x16x32_bf16(ac.v, bc.v, acc, 0, 0, 0);
    }
    lgkm_barrier();   // LDS reads done before next overwrite
  }

  // epilogue: ELU. C/D layout: col(N=f)=lane&15, row(M)=4*(lane>>4)+reg
#pragma unroll
  for (int qq = 0; qq < 4; ++qq) {
    const int rr = lg * 4 + qq;
    const float x = acc[qq];
    hout[(rowb + rr) * 64 + w * 16 + ln] = (x > 0.f) ? x : expm1f(x);
  }
}

extern "C" void kernel_launch(void* const* d_in, const int* in_sizes, int n_in,
                              void* d_out, int out_size, void* d_ws, size_t ws_size,
                              hipStream_t stream)
{
  const float* h   = (const float*)d_in[0];
  const int*   adj = (const int*)d_in[1];
  const float* W   = (const float*)d_in[2];
  const float* a   = (const float*)d_in[3];
  float* hout = (float*)d_out;
  float* att  = hout + (size_t)8 * 2048 * 64;

  char* ws = (char*)d_ws;
  unsigned short* WhT = (unsigned short*)ws;                    // 2 MB
  float* s1 = (float*)(ws + (size_t)(2u << 20));                // 64 KB each
  float* s2 = s1 + 16384;

  k0_wh   <<<dim3(32, 8),  256, 0, stream>>>(h, W, a, WhT, s1, s2);
  k12_main<<<dim3(128, 8), 256, 0, stream>>>(adj, WhT, s1, s2, hout, att);
}

// Round 14
// 116.605 us; speedup vs baseline: 1.0692x; 1.0692x over previous
//
#include <hip/hip_runtime.h>

#define GAT_ALPHA 0.2f
#define INV_N (1.0f / 2048.0f)

typedef float f32x4 __attribute__((ext_vector_type(4)));
typedef int   i32x4 __attribute__((ext_vector_type(4)));
typedef __bf16 bf16x8 __attribute__((ext_vector_type(8)));
typedef unsigned short us8 __attribute__((ext_vector_type(8)));
typedef unsigned short us4 __attribute__((ext_vector_type(4)));

__device__ __forceinline__ unsigned short f2bf(float x) {
  union { float f; unsigned u; } v; v.f = x;
  unsigned r = v.u + 0x7FFFu + ((v.u >> 16) & 1u);   // RNE
  return (unsigned short)(r >> 16);
}
__device__ __forceinline__ float lrelu(float x) {
  return fmaxf(x, 0.f) + GAT_ALPHA * fminf(x, 0.f);
}
__device__ __forceinline__ void lgkm_barrier() {
  asm volatile("s_waitcnt lgkmcnt(0)" ::: "memory");
  __builtin_amdgcn_s_barrier();
  __builtin_amdgcn_sched_barrier(0);
}

// ---------------- k0: Wh = h @ W (f32), s1/s2, WhT in bf16 [b][f][j] ----------------
__global__ __launch_bounds__(256)
void k0_wh(const float* __restrict__ h, const float* __restrict__ W,
           const float* __restrict__ a, unsigned short* __restrict__ WhT,
           float* __restrict__ s1g, float* __restrict__ s2g)
{
  __shared__ float h_s[64][132];
  __shared__ float W_s[128][64];
  __shared__ float wt_s[64][66];
  __shared__ float a_s[128];
  const int t = threadIdx.x;
  const int b = blockIdx.y;
  const int r0 = blockIdx.x * 64;

#pragma unroll
  for (int v = 0; v < 8; ++v) {
    int c = v * 256 + t;
    int k = c >> 4, fo = (c & 15) << 2;
    *(float4*)&W_s[k][fo] = *(const float4*)&W[k * 64 + fo];
  }
#pragma unroll
  for (int v = 0; v < 8; ++v) {
    int c = v * 256 + t;
    int r = c >> 5, ko = (c & 31) << 2;
    *(float4*)&h_s[r][ko] = *(const float4*)&h[((size_t)(b * 2048 + r0 + r)) * 128 + ko];
  }
  if (t < 128) a_s[t] = a[t];
  __syncthreads();

  const int tg = t >> 4;          // 0..15
  const int tf = (t & 15) << 2;   // f base
  float acc[4][4] = {};
#pragma unroll
  for (int k4 = 0; k4 < 32; ++k4) {
    float4 hv[4];
#pragma unroll
    for (int i = 0; i < 4; ++i)
      hv[i] = *(const float4*)&h_s[i * 16 + tg][k4 * 4];
#pragma unroll
    for (int kk = 0; kk < 4; ++kk) {
      float4 wv = *(const float4*)&W_s[k4 * 4 + kk][tf];
#pragma unroll
      for (int i = 0; i < 4; ++i) {
        float hx = ((const float*)&hv[i])[kk];
        acc[i][0] = fmaf(hx, wv.x, acc[i][0]);
        acc[i][1] = fmaf(hx, wv.y, acc[i][1]);
        acc[i][2] = fmaf(hx, wv.z, acc[i][2]);
        acc[i][3] = fmaf(hx, wv.w, acc[i][3]);
      }
    }
  }
#pragma unroll
  for (int i = 0; i < 4; ++i)
#pragma unroll
    for (int j = 0; j < 4; ++j)
      wt_s[tf + j][i * 16 + tg] = acc[i][j];
  __syncthreads();

  if (t < 64) {   // s1/s2 for row r = t (f32 exact)
    float v1 = 0.f, v2 = 0.f;
#pragma unroll 8
    for (int f = 0; f < 64; ++f) {
      float w = wt_s[f][t];
      v1 = fmaf(w, a_s[f], v1);
      v2 = fmaf(w, a_s[64 + f], v2);
    }
    s1g[b * 2048 + r0 + t] = v1;
    s2g[b * 2048 + r0 + t] = v2;
  }
  {  // WhT bf16 write, [b][f][j]
    int f = t >> 2, rb = (t & 3) << 4;
    unsigned short pk[16];
#pragma unroll
    for (int i = 0; i < 16; ++i) pk[i] = f2bf(wt_s[f][rb + i]);
    size_t base = ((size_t)(b * 64 + f)) * 2048 + r0 + rb;
    *(uint4*)&WhT[base]     = *(uint4*)&pk[0];
    *(uint4*)&WhT[base + 8] = *(uint4*)&pk[8];
  }
}

// ---------------- k12: fused stats + att write (nt) + PV MFMA + ELU ----------------
// R11 structure, ONE delta: NO z_s LDS staging — s2 read from global (8 KB/batch,
// L2-broadcast, the proven-R8 pattern). LDS 34.8 -> 25.8 KB => 6 blocks/CU
// (24 waves/CU vs 16). launch_bounds(256,6) pins VGPR <= 85.
__global__ __launch_bounds__(256, 6)
void k12_main(const int* __restrict__ adj, const unsigned short* __restrict__ WhT,
              const float* __restrict__ s1g, const float* __restrict__ s2g,
              float* __restrict__ hout, float* __restrict__ att)
{
  __shared__ unsigned short bm16[16][128];    // 4 KB: bit (j&15) of word j>>4
  __shared__ float s1_s[16], il_s[16];
  __shared__ unsigned short att_s[16][136];   // bf16 att tile (stride 272 B)
  __shared__ unsigned short wh_s[64][136];    // bf16 Wh tile [f][k]

  const int t = threadIdx.x;
  const int b = blockIdx.y;
  const int r0 = blockIdx.x * 16;
  const size_t rowb = (size_t)(b * 2048 + r0);
  const int r = t >> 4, q = t & 15;           // pass-1: 16 threads per row
  const int* __restrict__ arow = adj + (rowb + r) * 2048;
  const float* __restrict__ z = s2g + b * 2048;

  // issue first adj batch immediately (max read parallelism from t=0)
  i32x4 av0[4], av1[4];
#pragma unroll
  for (int k = 0; k < 4; ++k) av0[k] = *(const i32x4*)&arow[q * 16 + 4 * k];

  if (t < 16) s1_s[t] = s1g[rowb + t];
  const float s1v = s1g[rowb + r];

  // ---- pass 1: masks + denominator (8 int4 in flight via double buffer) ----
  float sum = 0.f;
#pragma unroll
  for (int c = 0; c < 8; ++c) {
    if (c < 7) {
#pragma unroll
      for (int k = 0; k < 4; ++k)
        av1[k] = *(const i32x4*)&arow[(c + 1) * 256 + q * 16 + 4 * k];
    }
    unsigned bits = 0;
#pragma unroll
    for (int k = 0; k < 4; ++k) {
      const float4 zz = *(const float4*)&z[c * 256 + q * 16 + 4 * k];
      const bool p0 = av0[k].x > 0, p1 = av0[k].y > 0;
      const bool p2 = av0[k].z > 0, p3 = av0[k].w > 0;
      bits |= (unsigned(p0) | (unsigned(p1) << 1) |
               (unsigned(p2) << 2) | (unsigned(p3) << 3)) << (4 * k);
      sum += p0 ? __expf(lrelu(s1v + zz.x)) : 0.f;
      sum += p1 ? __expf(lrelu(s1v + zz.y)) : 0.f;
      sum += p2 ? __expf(lrelu(s1v + zz.z)) : 0.f;
      sum += p3 ? __expf(lrelu(s1v + zz.w)) : 0.f;
    }
    bm16[r][c * 16 + q] = (unsigned short)bits;
#pragma unroll
    for (int k = 0; k < 4; ++k) av0[k] = av1[k];
  }
#pragma unroll
  for (int o = 1; o < 16; o <<= 1) sum += __shfl_xor(sum, o);
  if (q == 0) il_s[r] = (sum > 0.f) ? 1.f / sum : -1.f;  // -1: no neighbors -> 1/N
  lgkm_barrier();   // bm16 + il_s + s1_s visible

  // ---- pass 2: att write (nt) + PV; MFMA operands strictly in LDS (lgkm) ----
  const int w  = t >> 6, l = t & 63;
  const int ln = l & 15, lg = l >> 4;
  const int ff = t >> 4, ko = (t & 15) << 3;   // wh staging coords
  const int jj = (t & 31) << 2;
  const int rbase = t >> 5;
  f32x4 acc = {0.f, 0.f, 0.f, 0.f};

  for (int j0 = 0; j0 < 2048; j0 += 128) {
    // T14 (same-iter, proven): issue WhT loads early, LDS-write late
    uint4 wreg[4];
#pragma unroll
    for (int v = 0; v < 4; ++v)
      wreg[v] = *(const uint4*)&WhT[((size_t)(b * 64 + v * 16 + ff)) * 2048 + j0 + ko];

    // attention: 16 rows x 128 j; z from global (L2-hot), same value both halves
    const int j = j0 + jj;
    const float4 zv = *(const float4*)&z[j];
#pragma unroll
    for (int it = 0; it < 2; ++it) {
      const int rr = rbase + (it << 3);
      const float s1r = s1_s[rr], il = il_s[rr];
      const bool uni = (il < 0.f);
      const unsigned mb = (unsigned)bm16[rr][j >> 4] >> (j & 15);
      f32x4 o;
#define PW(dst, zz, k)                                              \
      { float e = __expf(lrelu(s1r + (zz))) * il;                   \
        dst = uni ? INV_N : (((mb >> (k)) & 1u) ? e : 0.f); }
      PW(o[0], zv.x, 0) PW(o[1], zv.y, 1) PW(o[2], zv.z, 2) PW(o[3], zv.w, 3)
#undef PW
      __builtin_nontemporal_store(o, (f32x4*)&att[(rowb + rr) * 2048 + j]);
      us4 pk;
      pk.x = f2bf(o[0]); pk.y = f2bf(o[1]); pk.z = f2bf(o[2]); pk.w = f2bf(o[3]);
      *(us4*)&att_s[rr][jj] = pk;
    }
    // late LDS write of Wh tile
#pragma unroll
    for (int v = 0; v < 4; ++v)
      *(uint4*)&wh_s[v * 16 + ff][ko] = wreg[v];

    lgkm_barrier();   // publish att_s + wh_s; nt att stores NOT drained
    // PV: wave w owns f-tile w; A from att_s, B from wh_s (same k-permutation)
#pragma unroll
    for (int ks = 0; ks < 4; ++ks) {
      union { us8 u; bf16x8 v; } ac, bc;
      ac.u = *(const us8*)&att_s[ln][ks * 32 + lg * 8];
      bc.u = *(const us8*)&wh_s[w * 16 + ln][ks * 32 + lg * 8];
      acc = __builtin_amdgcn_mfma_f32_16x16x32_bf16(ac.v, bc.v, acc, 0, 0, 0);
    }
    lgkm_barrier();   // LDS reads done before next overwrite
  }

  // epilogue: ELU. C/D layout: col(N=f)=lane&15, row(M)=4*(lane>>4)+reg
#pragma unroll
  for (int qq = 0; qq < 4; ++qq) {
    const int rr = lg * 4 + qq;
    const float x = acc[qq];
    hout[(rowb + rr) * 64 + w * 16 + ln] = (x > 0.f) ? x : expm1f(x);
  }
}

extern "C" void kernel_launch(void* const* d_in, const int* in_sizes, int n_in,
                              void* d_out, int out_size, void* d_ws, size_t ws_size,
                              hipStream_t stream)
{
  const float* h   = (const float*)d_in[0];
  const int*   adj = (const int*)d_in[1];
  const float* W   = (const float*)d_in[2];
  const float* a   = (const float*)d_in[3];
  float* hout = (float*)d_out;
  float* att  = hout + (size_t)8 * 2048 * 64;

  char* ws = (char*)d_ws;
  unsigned short* WhT = (unsigned short*)ws;                    // 2 MB
  float* s1 = (float*)(ws + (size_t)(2u << 20));                // 64 KB each
  float* s2 = s1 + 16384;

  k0_wh   <<<dim3(32, 8),  256, 0, stream>>>(h, W, a, WhT, s1, s2);
  k12_main<<<dim3(128, 8), 256, 0, stream>>>(adj, WhT, s1, s2, hout, att);
}

// Round 15
// 72.761 us; speedup vs baseline: 1.7135x; 1.6026x over previous
//
#include <hip/hip_runtime.h>

#define GAT_ALPHA 0.2f
#define INV_N (1.0f / 2048.0f)

typedef float f32x4 __attribute__((ext_vector_type(4)));
typedef __bf16 bf16x8 __attribute__((ext_vector_type(8)));
typedef unsigned short us8 __attribute__((ext_vector_type(8)));
typedef unsigned short us4 __attribute__((ext_vector_type(4)));

__device__ __forceinline__ unsigned short f2bf(float x) {
  union { float f; unsigned u; } v; v.f = x;
  unsigned r = v.u + 0x7FFFu + ((v.u >> 16) & 1u);   // RNE
  return (unsigned short)(r >> 16);
}
__device__ __forceinline__ float lrelu(float x) {
  return fmaxf(x, 0.f) + GAT_ALPHA * fminf(x, 0.f);
}
__device__ __forceinline__ void lgkm_barrier() {
  asm volatile("s_waitcnt lgkmcnt(0)" ::: "memory");
  __builtin_amdgcn_s_barrier();
  __builtin_amdgcn_sched_barrier(0);
}

// ---------------- k0: Wh = h @ W (f32), s1/s2, WhT in bf16 [b][f][j] ----------------
__global__ __launch_bounds__(256)
void k0_wh(const float* __restrict__ h, const float* __restrict__ W,
           const float* __restrict__ a, unsigned short* __restrict__ WhT,
           float* __restrict__ s1g, float* __restrict__ s2g)
{
  __shared__ float h_s[64][132];
  __shared__ float W_s[128][64];
  __shared__ float wt_s[64][66];
  __shared__ float a_s[128];
  const int t = threadIdx.x;
  const int b = blockIdx.y;
  const int r0 = blockIdx.x * 64;

#pragma unroll
  for (int v = 0; v < 8; ++v) {
    int c = v * 256 + t;
    int k = c >> 4, fo = (c & 15) << 2;
    *(float4*)&W_s[k][fo] = *(const float4*)&W[k * 64 + fo];
  }
#pragma unroll
  for (int v = 0; v < 8; ++v) {
    int c = v * 256 + t;
    int r = c >> 5, ko = (c & 31) << 2;
    *(float4*)&h_s[r][ko] = *(const float4*)&h[((size_t)(b * 2048 + r0 + r)) * 128 + ko];
  }
  if (t < 128) a_s[t] = a[t];
  __syncthreads();

  const int tg = t >> 4;          // 0..15
  const int tf = (t & 15) << 2;   // f base
  float acc[4][4] = {};
#pragma unroll
  for (int k4 = 0; k4 < 32; ++k4) {
    float4 hv[4];
#pragma unroll
    for (int i = 0; i < 4; ++i)
      hv[i] = *(const float4*)&h_s[i * 16 + tg][k4 * 4];
#pragma unroll
    for (int kk = 0; kk < 4; ++kk) {
      float4 wv = *(const float4*)&W_s[k4 * 4 + kk][tf];
#pragma unroll
      for (int i = 0; i < 4; ++i) {
        float hx = ((const float*)&hv[i])[kk];
        acc[i][0] = fmaf(hx, wv.x, acc[i][0]);
        acc[i][1] = fmaf(hx, wv.y, acc[i][1]);
        acc[i][2] = fmaf(hx, wv.z, acc[i][2]);
        acc[i][3] = fmaf(hx, wv.w, acc[i][3]);
      }
    }
  }
#pragma unroll
  for (int i = 0; i < 4; ++i)
#pragma unroll
    for (int j = 0; j < 4; ++j)
      wt_s[tf + j][i * 16 + tg] = acc[i][j];
  __syncthreads();

  if (t < 64) {   // s1/s2 for row r = t (f32 exact)
    float v1 = 0.f, v2 = 0.f;
#pragma unroll 8
    for (int f = 0; f < 64; ++f) {
      float w = wt_s[f][t];
      v1 = fmaf(w, a_s[f], v1);
      v2 = fmaf(w, a_s[64 + f], v2);
    }
    s1g[b * 2048 + r0 + t] = v1;
    s2g[b * 2048 + r0 + t] = v2;
  }
  {  // WhT bf16 write, [b][f][j]
    int f = t >> 2, rb = (t & 3) << 4;
    unsigned short pk[16];
#pragma unroll
    for (int i = 0; i < 16; ++i) pk[i] = f2bf(wt_s[f][rb + i]);
    size_t base = ((size_t)(b * 64 + f)) * 2048 + r0 + rb;
    *(uint4*)&WhT[base]     = *(uint4*)&pk[0];
    *(uint4*)&WhT[base + 8] = *(uint4*)&pk[8];
  }
}

// ---------------- k1: block-per-row (R8 verbatim), denom + bitmask ----------------
// bit convention: word[c*4 + q] bit l  <->  j = c*256 + 4*l + q
__global__ __launch_bounds__(256)
void k1_stats(const int* __restrict__ adj, const float* __restrict__ s1g,
              const float* __restrict__ s2g, float* __restrict__ lrow,
              unsigned long long* __restrict__ gmask)
{
  const int t = threadIdx.x;
  const int l = t & 63, wv = t >> 6;
  const int i = blockIdx.x, b = blockIdx.y;
  const size_t row = (size_t)(b * 2048 + i);

  const int4 a0 = *(const int4*)&adj[row * 2048 + 4 * t];
  const int4 a1 = *(const int4*)&adj[row * 2048 + 1024 + 4 * t];
  const float4 z0 = *(const float4*)&s2g[b * 2048 + 4 * t];
  const float4 z1 = *(const float4*)&s2g[b * 2048 + 1024 + 4 * t];

  unsigned long long m00 = __ballot(a0.x > 0), m01 = __ballot(a0.y > 0);
  unsigned long long m02 = __ballot(a0.z > 0), m03 = __ballot(a0.w > 0);
  unsigned long long m10 = __ballot(a1.x > 0), m11 = __ballot(a1.y > 0);
  unsigned long long m12 = __ballot(a1.z > 0), m13 = __ballot(a1.w > 0);
  if (l == 0) {
    unsigned long long* g = gmask + row * 32;
    ulonglong2 p0; p0.x = m00; p0.y = m01;
    ulonglong2 p1; p1.x = m02; p1.y = m03;
    ulonglong2 p2; p2.x = m10; p2.y = m11;
    ulonglong2 p3; p3.x = m12; p3.y = m13;
    *(ulonglong2*)&g[wv * 4]          = p0;
    *(ulonglong2*)&g[wv * 4 + 2]      = p1;
    *(ulonglong2*)&g[16 + wv * 4]     = p2;
    *(ulonglong2*)&g[16 + wv * 4 + 2] = p3;
  }

  const float s1v = s1g[row];
  float sum = 0.f;
  sum += (a0.x > 0) ? __expf(lrelu(s1v + z0.x)) : 0.f;
  sum += (a0.y > 0) ? __expf(lrelu(s1v + z0.y)) : 0.f;
  sum += (a0.z > 0) ? __expf(lrelu(s1v + z0.z)) : 0.f;
  sum += (a0.w > 0) ? __expf(lrelu(s1v + z0.w)) : 0.f;
  sum += (a1.x > 0) ? __expf(lrelu(s1v + z1.x)) : 0.f;
  sum += (a1.y > 0) ? __expf(lrelu(s1v + z1.y)) : 0.f;
  sum += (a1.z > 0) ? __expf(lrelu(s1v + z1.z)) : 0.f;
  sum += (a1.w > 0) ? __expf(lrelu(s1v + z1.w)) : 0.f;
#pragma unroll
  for (int o = 32; o > 0; o >>= 1) sum += __shfl_xor(sum, o);
  __shared__ float red2[4];
  if (l == 0) red2[wv] = sum;
  __syncthreads();
  if (t == 0) lrow[row] = red2[0] + red2[1] + red2[2] + red2[3];
}

// ---------------- k2: att write (nt) + partial PV; 16-row strips, wave-private wh_s,
//                  att_s double-buffered -> ONE lgkm barrier per iter ----------------
// Wave w owns f-tile w (16 f). wh_s[w] is PRIVATE to wave w (staged global->reg->
// ds_write, ordered by intra-wave lgkmcnt -> needs NO barrier). att_s[2] dbuf:
// writes to p^1 never collide with in-flight reads of p (slow wave's reads are
// complete before it passes the barrier -> reuse is safe).
__global__ __launch_bounds__(256)
void k2_att_pv(const unsigned long long* __restrict__ gmask,
               const unsigned short* __restrict__ WhT,
               const float* __restrict__ s1g, const float* __restrict__ s2g,
               const float* __restrict__ lrow,
               float* __restrict__ pp0, float* __restrict__ pp1,
               float* __restrict__ att)
{
  __shared__ unsigned long long bm_s[16][16];     // 2 KB (jh half: 16 words/row)
  __shared__ float s1_s[16], il_s[16];
  __shared__ unsigned short att_s[2][16][136];    // 8.7 KB dbuf
  __shared__ unsigned short wh_s[4][16][136];     // 17.4 KB, per-wave regions

  const int t = threadIdx.x;
  const int b = blockIdx.z;
  const int jh = blockIdx.y;
  const int jb = jh << 10;
  const int r0 = blockIdx.x * 16;
  const size_t rowb = (size_t)(b * 2048 + r0);

  bm_s[t >> 4][t & 15] = gmask[(rowb + (t >> 4)) * 32 + jh * 16 + (t & 15)];
  if (t < 16) {
    float L = lrow[rowb + t];
    s1_s[t] = s1g[rowb + t];
    il_s[t] = (L > 0.f) ? 1.f / L : -1.f;   // -1 sentinel: no neighbors -> uniform 1/N
  }
  __syncthreads();

  const int w  = t >> 6, l = t & 63;
  const int ln = l & 15, lg = l >> 4;
  const int jj = (t & 31) << 2;
  const int rbase = (t >> 5) & 7;
  // wh staging: load v covers rows w*16 + v*4 + lg, bytes ln*16 (fully coalesced)
  const unsigned short* __restrict__ wsrc =
      WhT + ((size_t)(b * 64 + w * 16)) * 2048;
  f32x4 acc = {0.f, 0.f, 0.f, 0.f};

  int p = 0;
  for (int j0 = jb; j0 < jb + 1024; j0 += 128) {
    // T14 (same-iter): issue this wave's wh loads early
    uint4 wreg[4];
#pragma unroll
    for (int v = 0; v < 4; ++v)
      wreg[v] = *(const uint4*)&wsrc[(size_t)(v * 4 + lg) * 2048 + j0 + ln * 8];

    // attention: 16 rows x 128 j; 8 elems/thread (rows rbase, rbase+8)
    const int j = j0 + jj;
    const float4 zv = *(const float4*)&s2g[b * 2048 + j];
    const int lc4 = ((j >> 8) & 3) << 2;
    const int pos = (j & 255) >> 2;
#pragma unroll
    for (int it = 0; it < 2; ++it) {
      const int rr = rbase + (it << 3);
      const float s1r = s1_s[rr], il = il_s[rr];
      const bool uni = (il < 0.f);
      const unsigned long long w0 = bm_s[rr][lc4 + 0];
      const unsigned long long w1 = bm_s[rr][lc4 + 1];
      const unsigned long long w2 = bm_s[rr][lc4 + 2];
      const unsigned long long w3 = bm_s[rr][lc4 + 3];
      f32x4 o;
#define PW(dst, zz, wq)                                             \
      { float e = __expf(lrelu(s1r + (zz))) * il;                   \
        dst = uni ? INV_N : ((((wq) >> pos) & 1ull) ? e : 0.f); }
      PW(o[0], zv.x, w0) PW(o[1], zv.y, w1) PW(o[2], zv.z, w2) PW(o[3], zv.w, w3)
#undef PW
      __builtin_nontemporal_store(o, (f32x4*)&att[(rowb + rr) * 2048 + j]);
      us4 pk;
      pk.x = f2bf(o[0]); pk.y = f2bf(o[1]); pk.z = f2bf(o[2]); pk.w = f2bf(o[3]);
      *(us4*)&att_s[p][rr][jj] = pk;
    }
    // wave-private wh_s write (intra-wave lgkm ordering; no barrier needed)
#pragma unroll
    for (int v = 0; v < 4; ++v)
      *(uint4*)&wh_s[w][v * 4 + lg][ln * 8] = wreg[v];

    lgkm_barrier();   // publish att_s[p]; nt stores NOT drained
    // PV: A from att_s[p], B from own wh_s region (same k-permutation)
#pragma unroll
    for (int ks = 0; ks < 4; ++ks) {
      union { us8 u; bf16x8 v; } ac, bc;
      ac.u = *(const us8*)&att_s[p][ln][ks * 32 + lg * 8];
      bc.u = *(const us8*)&wh_s[w][ln][ks * 32 + lg * 8];
      acc = __builtin_amdgcn_mfma_f32_16x16x32_bf16(ac.v, bc.v, acc, 0, 0, 0);
    }
    p ^= 1;
  }

  // partial write. C/D layout: col(N=f)=lane&15, row(M)=4*(lane>>4)+reg
  float* __restrict__ pp = (jh == 0) ? pp0 : pp1;
#pragma unroll
  for (int q = 0; q < 4; ++q) {
    const int rr = lg * 4 + q;
    pp[(rowb + rr) * 64 + w * 16 + ln] = acc[q];
  }
}

// ---------------- k3: hout = elu(pp0 + pp1) ----------------
__global__ __launch_bounds__(256)
void k3_elu(const float* __restrict__ pp0, const float* __restrict__ pp1,
            float* __restrict__ hout)
{
  const size_t idx = ((size_t)blockIdx.x * 256 + threadIdx.x) * 4;
  float4 a = *(const float4*)&pp0[idx];
  float4 c = *(const float4*)&pp1[idx];
  float4 o;
  float x;
  x = a.x + c.x; o.x = (x > 0.f) ? x : expm1f(x);
  x = a.y + c.y; o.y = (x > 0.f) ? x : expm1f(x);
  x = a.z + c.z; o.z = (x > 0.f) ? x : expm1f(x);
  x = a.w + c.w; o.w = (x > 0.f) ? x : expm1f(x);
  *(float4*)&hout[idx] = o;
}

extern "C" void kernel_launch(void* const* d_in, const int* in_sizes, int n_in,
                              void* d_out, int out_size, void* d_ws, size_t ws_size,
                              hipStream_t stream)
{
  const float* h   = (const float*)d_in[0];
  const int*   adj = (const int*)d_in[1];
  const float* W   = (const float*)d_in[2];
  const float* a   = (const float*)d_in[3];
  float* hout = (float*)d_out;
  float* att  = hout + (size_t)8 * 2048 * 64;

  char* ws = (char*)d_ws;
  unsigned short* WhT = (unsigned short*)ws;                    // 2 MB
  float* s1 = (float*)(ws + (size_t)(2u << 20));                // 64 KB each
  float* s2 = s1 + 16384;
  float* lr = s2 + 16384;
  unsigned long long* gmask =
      (unsigned long long*)(ws + (size_t)(2u << 20) + 3 * 65536); // 4 MB
  float* pp0 = (float*)(ws + (size_t)(2u << 20) + 3 * 65536 + (4u << 20)); // 4 MB
  float* pp1 = pp0 + (size_t)8 * 2048 * 64;                                // 4 MB

  k0_wh    <<<dim3(32, 8),     256, 0, stream>>>(h, W, a, WhT, s1, s2);
  k1_stats <<<dim3(2048, 8),   256, 0, stream>>>(adj, s1, s2, lr, gmask);
  k2_att_pv<<<dim3(128, 2, 8), 256, 0, stream>>>(gmask, WhT, s1, s2, lr, pp0, pp1, att);
  k3_elu   <<<dim3(1024),      256, 0, stream>>>(pp0, pp1, hout);
}